// Round 17
// baseline (954.345 us; speedup 1.0000x reference)
//
#include <hip/hip_runtime.h>
#include <hip/hip_fp16.h>
#include <cstdint>
#include <cstddef>

#define D_MODEL 512
#define N_HEADS 8
#define HEAD_E  64
#define SEQ_L   2048
#define BATCH   2
#define KSEL    38            // int(5*log(2048)) = 38
#define M_ROWS  (BATCH*SEQ_L) // 4096
#define SP      2050          // S row stride (f16)
#define CCAP    256           // candidate cap (4 per lane); overflow -> fixup

typedef short bf16x8 __attribute__((ext_vector_type(8)));
typedef float f32x4  __attribute__((ext_vector_type(4)));

static __device__ __forceinline__ unsigned short f2bf(float x) {
  uint32_t u = __float_as_uint(x);
  return (unsigned short)((u + 0x7FFF + ((u >> 16) & 1)) >> 16);  // RNE
}

// ---------------------------------------------------------------------------
// Fused QKV f32 GEMM, 128x128 tile / 8x8 micro: z=0:Q, z=1:K, z=2:V.
// C = x @ W.T + b. Q,K also emit bf16 copies.
// Per kk-step: 16 ds_read_b128 -> 256 FMA (ALU-bound ~73%).
// ---------------------------------------------------------------------------
__global__ __launch_bounds__(256) void gemm_qkv_kernel(
    const float* __restrict__ A,
    const float* __restrict__ Wq, const float* __restrict__ bq,
    const float* __restrict__ Wk, const float* __restrict__ bk,
    const float* __restrict__ Wv, const float* __restrict__ bv,
    float* __restrict__ Qf, float* __restrict__ Kf, float* __restrict__ Vf,
    unsigned short* __restrict__ Qh, unsigned short* __restrict__ Kh)
{
  const int z = blockIdx.z;
  const float* W    = (z == 0) ? Wq : ((z == 1) ? Wk : Wv);
  const float* bias = (z == 0) ? bq : ((z == 1) ? bk : bv);
  float* C          = (z == 0) ? Qf : ((z == 1) ? Kf : Vf);
  unsigned short* Ch = (z == 0) ? Qh : ((z == 1) ? Kh : nullptr);

  __shared__ float As[128][36];
  __shared__ float Ws[128][36];
  const int t  = threadIdx.x;
  const int tx = t & 15, ty = t >> 4;
  const int bm = blockIdx.y << 7, bn = blockIdx.x << 7;

  float acc[8][8] = {};

  for (int k0 = 0; k0 < D_MODEL; k0 += 32) {
    __syncthreads();
#pragma unroll
    for (int i = 0; i < 4; ++i) {
      int f = t + (i << 8);                 // 1024 float4 slots (128 rows x 8)
      int r = f >> 3, c = (f & 7) << 2;
      *(float4*)&As[r][c] = *(const float4*)&A[(size_t)(bm + r) * D_MODEL + k0 + c];
      *(float4*)&Ws[r][c] = *(const float4*)&W[(size_t)(bn + r) * D_MODEL + k0 + c];
    }
    __syncthreads();
#pragma unroll
    for (int kk = 0; kk < 32; kk += 4) {
      float4 av[8], wv[8];
#pragma unroll
      for (int i = 0; i < 8; ++i) av[i] = *(const float4*)&As[ty + 16 * i][kk];
#pragma unroll
      for (int j = 0; j < 8; ++j) wv[j] = *(const float4*)&Ws[tx + 16 * j][kk];
#pragma unroll
      for (int i = 0; i < 8; ++i)
#pragma unroll
        for (int j = 0; j < 8; ++j)
          acc[i][j] += av[i].x * wv[j].x + av[i].y * wv[j].y +
                       av[i].z * wv[j].z + av[i].w * wv[j].w;
    }
  }

#pragma unroll
  for (int i = 0; i < 8; ++i) {
    int row = bm + ty + 16 * i;
#pragma unroll
    for (int j = 0; j < 8; ++j) {
      int col = bn + tx + 16 * j;
      float v = acc[i][j] + bias[col];
      size_t idx = (size_t)row * D_MODEL + col;
      C[idx] = v;
      if (Ch) Ch[idx] = f2bf(v);
    }
  }
}

// ---------------------------------------------------------------------------
// f32 GEMM (output projection), 128x128 tile / 8x8 micro: C = A @ W.T + b
// ---------------------------------------------------------------------------
__global__ __launch_bounds__(256) void gemm_bias_kernel(
    const float* __restrict__ A, const float* __restrict__ W,
    const float* __restrict__ bias, float* __restrict__ C,
    int M, int N, int K)
{
  __shared__ float As[128][36];
  __shared__ float Ws[128][36];
  const int t  = threadIdx.x;
  const int tx = t & 15, ty = t >> 4;
  const int bm = blockIdx.y << 7, bn = blockIdx.x << 7;

  float acc[8][8] = {};

  for (int k0 = 0; k0 < K; k0 += 32) {
    __syncthreads();
#pragma unroll
    for (int i = 0; i < 4; ++i) {
      int f = t + (i << 8);
      int r = f >> 3, c = (f & 7) << 2;
      *(float4*)&As[r][c] = *(const float4*)&A[(size_t)(bm + r) * K + k0 + c];
      *(float4*)&Ws[r][c] = *(const float4*)&W[(size_t)(bn + r) * K + k0 + c];
    }
    __syncthreads();
#pragma unroll
    for (int kk = 0; kk < 32; kk += 4) {
      float4 av[8], wv[8];
#pragma unroll
      for (int i = 0; i < 8; ++i) av[i] = *(const float4*)&As[ty + 16 * i][kk];
#pragma unroll
      for (int j = 0; j < 8; ++j) wv[j] = *(const float4*)&Ws[tx + 16 * j][kk];
#pragma unroll
      for (int i = 0; i < 8; ++i)
#pragma unroll
        for (int j = 0; j < 8; ++j)
          acc[i][j] += av[i].x * wv[j].x + av[i].y * wv[j].y +
                       av[i].z * wv[j].z + av[i].w * wv[j].w;
    }
  }

#pragma unroll
  for (int i = 0; i < 8; ++i) {
    int row = bm + ty + 16 * i;
#pragma unroll
    for (int j = 0; j < 8; ++j) {
      int col = bn + tx + 16 * j;
      C[(size_t)row * N + col] = acc[i][j] + bias[col];
    }
  }
}

// ---------------------------------------------------------------------------
// Per-(b,h,e) max |K_e| over keys — feeds the provable bf16-error margin.
// ---------------------------------------------------------------------------
__global__ __launch_bounds__(256) void kemax_kernel(
    const float* __restrict__ Kf, float* __restrict__ kemax)
{
  const int bh = blockIdx.x;
  const int b = bh >> 3, h = bh & 7;
  const int e = threadIdx.x & 63, chunk = threadIdx.x >> 6;
  const float* base = Kf + ((size_t)b * SEQ_L) * D_MODEL + h * HEAD_E + e;
  float mx = 0.f;
  for (int k = chunk * 512; k < chunk * 512 + 512; ++k)
    mx = fmaxf(mx, fabsf(base[(size_t)k * D_MODEL]));
  __shared__ float red[4][64];
  red[chunk][e] = mx;
  __syncthreads();
  if (threadIdx.x < 64) {
    float m0 = fmaxf(fmaxf(red[0][threadIdx.x], red[1][threadIdx.x]),
                     fmaxf(red[2][threadIdx.x], red[3][threadIdx.x]));
    kemax[bh * 64 + threadIdx.x] = m0;
  }
}

// ---------------------------------------------------------------------------
// Main ProbSparse attention — R15 version verbatim (proven fastest: 397 us).
// 16 queries/block, wave w handles queries 2w, 2w+1. CCAP 256.
// ---------------------------------------------------------------------------
__global__ __launch_bounds__(512) void attn_main(
    const float* __restrict__ Qf, const float* __restrict__ Kf,
    const float* __restrict__ Vf,
    const unsigned short* __restrict__ Qh, const unsigned short* __restrict__ Kh,
    const float* __restrict__ kemax, float* __restrict__ AO,
    int* __restrict__ nflag, int* __restrict__ flagged)
{
  __shared__ __half  S[16][SP];          // 65600 B approx scores
  __shared__ short   cis2[8][CCAP];      // captured candidate indices
  __shared__ float   cvs[8][64];         // exact candidates (post bisect)
  __shared__ short   cis[8][64];
  __shared__ float   qrowL[16][64];      // f32 q rows (hoisted)
  __shared__ float   kemaxL[64];

  const int t    = threadIdx.x;
  const int w    = t >> 6;
  const int l    = t & 63;

  // XCD-affine decode
  const int wg   = blockIdx.x;
  const int xcd  = wg & 7;
  const int idx  = wg >> 3;
  const int bh   = xcd + 8 * (idx >> 7);
  const int qblk = idx & 127;
  const int b    = bh >> 3, h = bh & 7;
  const int q0   = qblk << 4;
  const size_t rowbase = (size_t)b * SEQ_L;

  if (t < 64) kemaxL[t] = kemax[bh * 64 + t];

  // hoist both q-row loads (latency overlaps the MFMA scan)
  {
    const float* qb = Qf + (rowbase + q0 + 2 * w) * D_MODEL + h * HEAD_E;
    qrowL[2 * w][l]     = qb[l];
    qrowL[2 * w + 1][l] = qb[D_MODEL + l];
  }

  // ---- MFMA score scan: wave w covers keys [w*256, w*256+256) ----
  {
    const int lo16 = l & 15, grp = l >> 4;
    const unsigned short* qrow =
        Qh + (rowbase + q0 + lo16) * D_MODEL + h * HEAD_E;
    bf16x8 a0 = *(const bf16x8*)&qrow[grp * 8];
    bf16x8 a1 = *(const bf16x8*)&qrow[32 + grp * 8];

    const int kbase = w * 256;
#pragma unroll
    for (int kt = 0; kt < 4; ++kt) {
#pragma unroll
      for (int kc = 0; kc < 4; ++kc) {
        const int key0 = kbase + kt * 64 + kc * 16 + lo16;
        const unsigned short* krow =
            Kh + (rowbase + key0) * D_MODEL + h * HEAD_E;
        bf16x8 b0 = *(const bf16x8*)&krow[grp * 8];
        bf16x8 b1 = *(const bf16x8*)&krow[32 + grp * 8];
        f32x4 acc = {0.f, 0.f, 0.f, 0.f};
        acc = __builtin_amdgcn_mfma_f32_16x16x32_bf16(a0, b0, acc, 0, 0, 0);
        acc = __builtin_amdgcn_mfma_f32_16x16x32_bf16(a1, b1, acc, 0, 0, 0);
#pragma unroll
        for (int r = 0; r < 4; ++r)
          S[grp * 4 + r][key0] = __float2half(acc[r] * 0.125f);
      }
    }
  }
  __syncthreads();

  // ---- selection: wave w handles queries 2w, 2w+1 ----
  for (int qq = 0; qq < 2; ++qq) {
    const int q   = 2 * w + qq;
    const int qid = bh * SEQ_L + q0 + q;

    float v[32];
#pragma unroll
    for (int j = 0; j < 32; ++j) v[j] = __half2float(S[q][(j << 6) + l]);

    // fused max / mean / var reduce
    float m = v[0], s1 = 0.f, s2 = 0.f;
#pragma unroll
    for (int j = 0; j < 32; ++j) {
      m = fmaxf(m, v[j]); s1 += v[j]; s2 += v[j] * v[j];
    }
#pragma unroll
    for (int off = 1; off < 64; off <<= 1) {
      m  = fmaxf(m, __shfl_xor(m, off));
      s1 += __shfl_xor(s1, off);
      s2 += __shfl_xor(s2, off);
    }
    const float mu = s1 * (1.0f / 2048.0f);
    const float sg = sqrtf(fmaxf(s2 * (1.0f / 2048.0f) - mu * mu, 0.f));
    const float lo = mu + 1.863f * sg;   // targets count ~ 64

    // ONE verify countge
    int C = 0;
#pragma unroll
    for (int j = 0; j < 32; ++j) C += (v[j] >= lo) ? 1 : 0;
#pragma unroll
    for (int off = 1; off < 64; off <<= 1) C += __shfl_xor(C, off);

    bool punt = (C < 40) | (C > 176);
    int base = 0;
    if (!punt) {
      // provable margin capture (unchanged constants)
      float red = fabsf(qrowL[q][l]) * kemaxL[l];
#pragma unroll
      for (int off = 1; off < 64; off <<= 1) red += __shfl_xor(red, off);
      const float lo2 = lo - (red * 0.0025f + 0.008f);
#pragma unroll
      for (int j = 0; j < 32; ++j) {
        bool in = (v[j] >= lo2);
        unsigned long long mk = __ballot(in);
        if (in) {
          int pos = base + (int)__popcll(mk & ((1ull << l) - 1ull));
          if (pos < CCAP) cis2[w][pos] = (short)((j << 6) | l);
        }
        base += (int)__popcll(mk);
      }
      punt = (base > CCAP);
    }
    if (punt) {
      if (l == 0) { int p = atomicAdd(nflag, 1); flagged[p] = qid; }
      continue;
    }

    // ---- exact f32 rescore of captured candidates (4 per lane) ----
    const int count2 = base;
    const int i0 = l, i1 = 64 + l, i2 = 128 + l, i3 = 192 + l;
    const int idx0 = (i0 < count2) ? (int)cis2[w][i0] : 0;
    const int idx1 = (i1 < count2) ? (int)cis2[w][i1] : 0;
    const int idx2 = (i2 < count2) ? (int)cis2[w][i2] : 0;
    const int idx3 = (i3 < count2) ? (int)cis2[w][i3] : 0;
    float e0 = -3.0e38f, e1 = -3.0e38f, e2 = -3.0e38f, e3 = -3.0e38f;
    {
      const float* kr0 = Kf + (rowbase + idx0) * D_MODEL + h * HEAD_E;
      const float* kr1 = Kf + (rowbase + idx1) * D_MODEL + h * HEAD_E;
      const float* kr2 = Kf + (rowbase + idx2) * D_MODEL + h * HEAD_E;
      const float* kr3 = Kf + (rowbase + idx3) * D_MODEL + h * HEAD_E;
      float r0 = 0.f, r1 = 0.f, r2 = 0.f, r3 = 0.f;
#pragma unroll
      for (int e4 = 0; e4 < 16; ++e4) {
        float4 qv = *(const float4*)&qrowL[q][e4 * 4];
        float4 k0 = *(const float4*)&kr0[e4 * 4];
        float4 k1 = *(const float4*)&kr1[e4 * 4];
        float4 k2 = *(const float4*)&kr2[e4 * 4];
        float4 k3 = *(const float4*)&kr3[e4 * 4];
        r0 += qv.x * k0.x + qv.y * k0.y + qv.z * k0.z + qv.w * k0.w;
        r1 += qv.x * k1.x + qv.y * k1.y + qv.z * k1.z + qv.w * k1.w;
        r2 += qv.x * k2.x + qv.y * k2.y + qv.z * k2.z + qv.w * k2.w;
        r3 += qv.x * k3.x + qv.y * k3.y + qv.z * k3.z + qv.w * k3.w;
      }
      if (i0 < count2) e0 = r0 * 0.125f;
      if (i1 < count2) e1 = r1 * 0.125f;
      if (i2 < count2) e2 = r2 * 0.125f;
      if (i3 < count2) e3 = r3 * 0.125f;
    }

    // exact bisect to count in [40, 64]
    float hiv = fmaxf(fmaxf(e0, e1), fmaxf(e2, e3));
    float lov = fminf(fminf((i0 < count2) ? e0 : 3.0e38f,
                            (i1 < count2) ? e1 : 3.0e38f),
                      fminf((i2 < count2) ? e2 : 3.0e38f,
                            (i3 < count2) ? e3 : 3.0e38f));
#pragma unroll
    for (int off = 1; off < 64; off <<= 1) {
      hiv = fmaxf(hiv, __shfl_xor(hiv, off));
      lov = fminf(lov, __shfl_xor(lov, off));
    }
    lov -= 1e-3f;
    for (int it = 0; it < 30; ++it) {
      int c = (int)__popcll(__ballot(e0 >= lov)) +
              (int)__popcll(__ballot(e1 >= lov)) +
              (int)__popcll(__ballot(e2 >= lov)) +
              (int)__popcll(__ballot(e3 >= lov));
      if (c <= 64) break;
      float mid = 0.5f * (lov + hiv);
      int cm = (int)__popcll(__ballot(e0 >= mid)) +
               (int)__popcll(__ballot(e1 >= mid)) +
               (int)__popcll(__ballot(e2 >= mid)) +
               (int)__popcll(__ballot(e3 >= mid));
      if (cm >= 40) lov = mid; else hiv = mid;
    }

    // compact exact-selected into cvs/cis (key order preserved)
    int C2;
    {
      bool in0 = (e0 >= lov);
      bool in1 = (e1 >= lov);
      bool in2 = (e2 >= lov);
      bool in3 = (e3 >= lov);
      unsigned long long m0 = __ballot(in0);
      unsigned long long m1 = __ballot(in1);
      unsigned long long m2 = __ballot(in2);
      unsigned long long m3 = __ballot(in3);
      int tot0 = (int)__popcll(m0), tot1 = (int)__popcll(m1);
      int tot2 = (int)__popcll(m2);
      if (in0) {
        int p = (int)__popcll(m0 & ((1ull << l) - 1ull));
        if (p < 64) { cvs[w][p] = e0; cis[w][p] = (short)idx0; }
      }
      if (in1) {
        int p = tot0 + (int)__popcll(m1 & ((1ull << l) - 1ull));
        if (p < 64) { cvs[w][p] = e1; cis[w][p] = (short)idx1; }
      }
      if (in2) {
        int p = tot0 + tot1 + (int)__popcll(m2 & ((1ull << l) - 1ull));
        if (p < 64) { cvs[w][p] = e2; cis[w][p] = (short)idx2; }
      }
      if (in3) {
        int p = tot0 + tot1 + tot2 + (int)__popcll(m3 & ((1ull << l) - 1ull));
        if (p < 64) { cvs[w][p] = e3; cis[w][p] = (short)idx3; }
      }
      int tot = tot0 + tot1 + tot2 + (int)__popcll(m3);
      C2 = (tot < 64) ? tot : 64;
    }

    float cval = (l < C2) ? cvs[w][l] : -3.0e38f;
    int   cidx = (l < C2) ? (int)cis[w][l] : (2 * SEQ_L + l);

    // bitonic sort 64: value desc, index asc
#pragma unroll
    for (int sz = 2; sz <= 64; sz <<= 1) {
#pragma unroll
      for (int st = sz >> 1; st >= 1; st >>= 1) {
        float ov = __shfl_xor(cval, st);
        int   oi = __shfl_xor(cidx, st);
        bool ob    = (ov > cval) || ((ov == cval) && (oi < cidx));
        bool dir   = ((l & sz) == 0);
        bool lower = ((l & st) == 0);
        if (ob == (lower == dir)) { cval = ov; cidx = oi; }
      }
    }

    const float m_ex = __shfl(cval, 0);
    const float v37  = __shfl(cval, 37);
    const float v38  = __shfl(cval, 38);
    if (v37 - v38 < 2e-5f) {           // tight boundary -> fixup
      if (l == 0) { int p = atomicAdd(nflag, 1); flagged[p] = qid; }
      continue;
    }

    float myw = (l < KSEL) ? __expf(cval - m_ex) : 0.f;
    float psum = myw;
#pragma unroll
    for (int off = 1; off < 64; off <<= 1) psum += __shfl_xor(psum, off);
    const float inv = 1.0f / psum;

    // ---- PV: branchless, 8 gather loads in flight per batch ----
    const float* Vb = Vf + rowbase * D_MODEL + h * HEAD_E;
    float acc = 0.f;
    for (int j0 = 0; j0 < 40; j0 += 8) {
      float wv8[8]; const float* vp8[8];
#pragma unroll
      for (int u = 0; u < 8; ++u) {
        wv8[u] = __shfl(myw, j0 + u);
        int sj = __shfl(cidx, j0 + u) & (SEQ_L - 1);
        vp8[u] = Vb + (size_t)sj * D_MODEL + l;
      }
      float vv8[8];
#pragma unroll
      for (int u = 0; u < 8; ++u) vv8[u] = *vp8[u];
#pragma unroll
      for (int u = 0; u < 8; ++u) acc = fmaf(wv8[u], vv8[u], acc);
    }
    AO[(rowbase + q0 + q) * D_MODEL + h * HEAD_E + l] = acc * inv;
  }
}

// ---------------------------------------------------------------------------
// Fixup: 8-wave cooperative per query (unchanged, proven).
// ---------------------------------------------------------------------------
__global__ __launch_bounds__(512) void attn_fixup(
    const float* __restrict__ Qf, const float* __restrict__ Kf,
    const float* __restrict__ Vf,
    const float* __restrict__ x,
    const float* __restrict__ Wq, const float* __restrict__ bq,
    const float* __restrict__ Wk, const float* __restrict__ bk,
    float* __restrict__ AO,
    const int* __restrict__ nflag, const int* __restrict__ flagged)
{
  __shared__ float  Kt[8][2048];    // per-wave swizzled 32-key tile, 8 x 8 KB
  __shared__ float  Sf[SEQ_L];      // exact f32 scores, 8 KB
  __shared__ float  qr[64];
  __shared__ double qdL[64];
  __shared__ double uL[512];
  __shared__ double dL[64];
  __shared__ int    ciL[64];
  __shared__ int    C2s;

  const int t = threadIdx.x;
  const int w = t >> 6;
  const int l = t & 63;
  const int n = *nflag;

  for (int s = blockIdx.x; s < n; s += gridDim.x) {
    const int qid  = flagged[s];
    const int bh   = qid >> 11, qrow = qid & (SEQ_L - 1);
    const int b    = bh >> 3, h = bh & 7;
    const size_t rowbase = (size_t)b * SEQ_L;
    const float* Kb = Kf + rowbase * D_MODEL + h * HEAD_E;
    const float* xr = x + (rowbase + qrow) * D_MODEL;

    if (t < 64) qr[t] = Qf[(rowbase + qrow) * D_MODEL + h * HEAD_E + t];
    float xreg[8];
#pragma unroll
    for (int jc = 0; jc < 8; ++jc) xreg[jc] = xr[(jc << 6) + l];
    __syncthreads();

    // lane's dim-half Q fragments
    const int hf = l >> 5, k32 = l & 31;
    float4 q_r[8];
#pragma unroll
    for (int i = 0; i < 8; ++i) q_r[i] = *(const float4*)&qr[(hf * 8 + i) * 4];

    float* Ktw = &Kt[w][0];

    // ---- exact f32 K-scan: wave w owns keys [256w, 256w+256), 8 tiles of 32 ----
    for (int ti = 0; ti < 8; ++ti) {
      const int kbase = w * 256 + ti * 32;
      __syncthreads();                         // uniform; guards Ktw reuse
#pragma unroll
      for (int i = 0; i < 8; ++i) {
        int f = (i << 6) + l;                  // 512 float4 slots (32 rows x 16)
        int r = f >> 4, c4 = f & 15;
        ((float4*)Ktw)[(r << 4) | (c4 ^ (r & 15))] =
            *(const float4*)&Kb[(size_t)(kbase + r) * D_MODEL + (c4 << 2)];
      }
      __syncthreads();
      float p0 = 0.f, p1 = 0.f;
#pragma unroll
      for (int i = 0; i < 8; i += 2) {
        int e4a = hf * 8 + i, e4b = e4a + 1;
        float4 ka = ((const float4*)Ktw)[(k32 << 4) | (e4a ^ (k32 & 15))];
        float4 kb = ((const float4*)Ktw)[(k32 << 4) | (e4b ^ (k32 & 15))];
        p0 += q_r[i].x*ka.x + q_r[i].y*ka.y + q_r[i].z*ka.z + q_r[i].w*ka.w;
        p1 += q_r[i+1].x*kb.x + q_r[i+1].y*kb.y + q_r[i+1].z*kb.z + q_r[i+1].w*kb.w;
      }
      float p = p0 + p1;
      p += __shfl_xor(p, 32);                  // combine dim-halves
      if (l < 32) Sf[kbase + k32] = p * 0.125f;
    }
    __syncthreads();

    // ---- qd phase: wave w computes qdL[8w .. 8w+8) ----
    for (int sub = 0; sub < 8; ++sub) {
      const int he = w * 8 + sub;
      const float* wqr = Wq + (size_t)(h * HEAD_E + he) * D_MODEL;
      double p = 0.0;
#pragma unroll
      for (int jc = 0; jc < 8; ++jc)
        p += (double)wqr[(jc << 6) + l] * (double)xreg[jc];
#pragma unroll
      for (int off = 1; off < 64; off <<= 1) p += __shfl_xor(p, off);
      if (l == 0) qdL[he] = p + (double)bq[h * HEAD_E + he];
    }
    __syncthreads();                            // qdL complete

    // ---- u phase: thread t owns j=t; coalesced column accumulate ----
    {
      double u = 0.0;
#pragma unroll 8
      for (int e = 0; e < 64; ++e)
        u += qdL[e] * (double)Wk[(size_t)(h * HEAD_E + e) * D_MODEL + t];
      uL[t] = u;
    }

    // ---- selection on wave 0 (bisect + compact, from Sf) ----
    if (w == 0) {
      float v[32];
#pragma unroll
      for (int j = 0; j < 32; ++j) v[j] = Sf[(j << 6) + l];

      float hiv = v[0], lov = v[0];
#pragma unroll
      for (int j = 1; j < 32; ++j) { hiv = fmaxf(hiv, v[j]); lov = fminf(lov, v[j]); }
#pragma unroll
      for (int off = 1; off < 64; off <<= 1) {
        hiv = fmaxf(hiv, __shfl_xor(hiv, off));
        lov = fminf(lov, __shfl_xor(lov, off));
      }
      lov -= 1e-3f;
      for (int it = 0; it < 30; ++it) {
        int c = 0;
#pragma unroll
        for (int j = 0; j < 32; ++j) c += (v[j] >= lov) ? 1 : 0;
#pragma unroll
        for (int off = 1; off < 64; off <<= 1) c += __shfl_xor(c, off);
        if (c <= 64) break;
        float mid = 0.5f * (lov + hiv);
        int cm = 0;
#pragma unroll
        for (int j = 0; j < 32; ++j) cm += (v[j] >= mid) ? 1 : 0;
#pragma unroll
        for (int off = 1; off < 64; off <<= 1) cm += __shfl_xor(cm, off);
        if (cm >= 40) lov = mid; else hiv = mid;
      }

      int bb = 0;
#pragma unroll
      for (int j = 0; j < 32; ++j) {
        bool in = (v[j] >= lov);
        unsigned long long mk = __ballot(in);
        if (in) {
          int pos = bb + (int)__popcll(mk & ((1ull << l) - 1ull));
          if (pos < 64) ciL[pos] = (j << 6) + l;
        }
        bb += (int)__popcll(mk);
      }
      if (l == 0) C2s = (bb < 64) ? bb : 64;
    }
    __syncthreads();                            // uL, ciL, C2s complete

    const int C2 = C2s;

    // qkb (per wave, from qdL)
    double qkb = qdL[l] * (double)bk[h * HEAD_E + l];
#pragma unroll
    for (int off = 1; off < 64; off <<= 1) qkb += __shfl_xor(qkb, off);

    // ---- s_c phase: wave w owns candidates 8w .. 8w+8 ----
    for (int sub = 0; sub < 8; ++sub) {
      const int c = w * 8 + sub;
      const int row = (c < C2) ? ciL[c] : 0;
      const float* xc = x + (rowbase + row) * D_MODEL + l;
      double p = 0.0;
#pragma unroll
      for (int jc = 0; jc < 8; ++jc)
        p += uL[(jc << 6) + l] * (double)xc[jc << 6];
#pragma unroll
      for (int off = 1; off < 64; off <<= 1) p += __shfl_xor(p, off);
      if (l == 0) dL[c] = (c < C2) ? (qkb + p) * 0.125 : -1.0e300;
    }
    __syncthreads();                            // dL complete

    // ---- rank / softmax / PV on wave 0 ----
    if (w == 0) {
      double d = dL[l];
      int myi = (l < C2) ? ciL[l] : (2 * SEQ_L + l);
      double mxd = -1.0e300; int rank = 0;
      for (int j = 0; j < 64; ++j) {
        double dj = dL[j];
        int    ij = (j < C2) ? ciL[j] : (2 * SEQ_L + j);
        if (dj > mxd) mxd = dj;
        rank += (dj > d) || ((dj == d) && (ij < myi));
      }
      float myw = (l < C2 && rank < KSEL) ? __expf((float)(d - mxd)) : 0.f;

      float psum = myw;
#pragma unroll
      for (int off = 1; off < 64; off <<= 1) psum += __shfl_xor(psum, off);
      const float inv = 1.0f / psum;

      const float* Vb = Vf + rowbase * D_MODEL + h * HEAD_E;
      float acc = 0.f;
      for (int j0 = 0; j0 < 64; j0 += 8) {
        float wv8[8]; const float* vp8[8];
#pragma unroll
        for (int u8 = 0; u8 < 8; ++u8) {
          wv8[u8] = __shfl(myw, j0 + u8);
          int sj = __shfl(myi, j0 + u8) & (SEQ_L - 1);
          vp8[u8] = Vb + (size_t)sj * D_MODEL + l;
        }
        float vv8[8];
#pragma unroll
        for (int u8 = 0; u8 < 8; ++u8) vv8[u8] = *vp8[u8];
#pragma unroll
        for (int u8 = 0; u8 < 8; ++u8) acc = fmaf(wv8[u8], vv8[u8], acc);
      }
      AO[(rowbase + qrow) * D_MODEL + h * HEAD_E + l] = acc * inv;
    }
    __syncthreads();                            // protect LDS before next query
  }
}

// ---------------------------------------------------------------------------
extern "C" void kernel_launch(void* const* d_in, const int* in_sizes, int n_in,
                              void* d_out, int out_size, void* d_ws, size_t ws_size,
                              hipStream_t stream) {
  const float* x  = (const float*)d_in[0];
  const float* Wq = (const float*)d_in[1];
  const float* bq = (const float*)d_in[2];
  const float* Wk = (const float*)d_in[3];
  const float* bk = (const float*)d_in[4];
  const float* Wv = (const float*)d_in[5];
  const float* bv = (const float*)d_in[6];
  const float* Wo = (const float*)d_in[7];
  const float* bo = (const float*)d_in[8];
  float* out = (float*)d_out;

  char* ws = (char*)d_ws;
  const size_t MATB = (size_t)M_ROWS * D_MODEL * 4;  // 8 MB
  float* Qf = (float*)ws;
  float* Kf = (float*)(ws + MATB);
  float* Vf = (float*)(ws + 2 * MATB);
  float* AO = (float*)(ws + 3 * MATB);
  unsigned short* Qh = (unsigned short*)(ws + 4 * MATB);            // 4 MB
  unsigned short* Kh = (unsigned short*)(ws + 4 * MATB + MATB / 2); // 4 MB
  float* kemax = (float*)(ws + 5 * MATB);                           // 4 KB
  int* nflag   = (int*)(ws + 5 * MATB + 4096);
  int* flagged = (int*)(ws + 5 * MATB + 8192);                      // 128 KB

  hipMemsetAsync(nflag, 0, 64, stream);

  dim3 qkvgrid(D_MODEL / 128, M_ROWS / 128, 3);   // (4, 32, 3)
  gemm_qkv_kernel<<<qkvgrid, 256, 0, stream>>>(
      x, Wq, bq, Wk, bk, Wv, bv, Qf, Kf, Vf, Qh, Kh);

  kemax_kernel<<<dim3(BATCH * N_HEADS), 256, 0, stream>>>(Kf, kemax);

  attn_main<<<dim3(SEQ_L / 16 * BATCH * N_HEADS), 512, 0, stream>>>(
      Qf, Kf, Vf, Qh, Kh, kemax, AO, nflag, flagged);

  attn_fixup<<<dim3(1024), 512, 0, stream>>>(
      Qf, Kf, Vf, x, Wq, bq, Wk, bk, AO, nflag, flagged);

  dim3 ggrid(D_MODEL / 128, M_ROWS / 128);        // (4, 32)
  gemm_bias_kernel<<<ggrid, 256, 0, stream>>>(AO, Wo, bo, out, M_ROWS, D_MODEL, D_MODEL);
}

// Round 18
// 659.106 us; speedup vs baseline: 1.4479x; 1.4479x over previous
//
#include <hip/hip_runtime.h>
#include <hip/hip_fp16.h>
#include <cstdint>
#include <cstddef>

#define D_MODEL 512
#define N_HEADS 8
#define HEAD_E  64
#define SEQ_L   2048
#define BATCH   2
#define KSEL    38            // int(5*log(2048)) = 38
#define M_ROWS  (BATCH*SEQ_L) // 4096
#define SP      2050          // S row stride (f16)
#define CCAP    128           // candidate cap (2 per lane); overflow -> fixup

typedef short bf16x8 __attribute__((ext_vector_type(8)));
typedef float f32x4  __attribute__((ext_vector_type(4)));

static __device__ __forceinline__ unsigned short f2bf(float x) {
  uint32_t u = __float_as_uint(x);
  return (unsigned short)((u + 0x7FFF + ((u >> 16) & 1)) >> 16);  // RNE
}
static __device__ __forceinline__ float bf2f(unsigned short h) {
  return __uint_as_float((uint32_t)h << 16);
}

// ---------------------------------------------------------------------------
// Fused QKV f32 GEMM (R15-proven 64x64 tile): z=0:Q, z=1:K, z=2:V.
// C = x @ W.T + b. Q,K also emit split-bf16 (hi + lo residual) copies.
// ---------------------------------------------------------------------------
__global__ __launch_bounds__(256) void gemm_qkv_kernel(
    const float* __restrict__ A,
    const float* __restrict__ Wq, const float* __restrict__ bq,
    const float* __restrict__ Wk, const float* __restrict__ bk,
    const float* __restrict__ Wv, const float* __restrict__ bv,
    float* __restrict__ Qf, float* __restrict__ Kf, float* __restrict__ Vf,
    unsigned short* __restrict__ Qh, unsigned short* __restrict__ Kh,
    unsigned short* __restrict__ Qlo, unsigned short* __restrict__ Klo)
{
  const int z = blockIdx.z;
  const float* W    = (z == 0) ? Wq : ((z == 1) ? Wk : Wv);
  const float* bias = (z == 0) ? bq : ((z == 1) ? bk : bv);
  float* C          = (z == 0) ? Qf : ((z == 1) ? Kf : Vf);
  unsigned short* Ch = (z == 0) ? Qh : ((z == 1) ? Kh : nullptr);
  unsigned short* Cl = (z == 0) ? Qlo : ((z == 1) ? Klo : nullptr);

  __shared__ float As[64][36];
  __shared__ float Ws[64][36];
  const int t  = threadIdx.x;
  const int tx = t & 15, ty = t >> 4;
  const int bm = blockIdx.y << 6, bn = blockIdx.x << 6;

  float acc[4][4] = {};

  for (int k0 = 0; k0 < D_MODEL; k0 += 32) {
    __syncthreads();
#pragma unroll
    for (int i = 0; i < 2; ++i) {
      int f = t + (i << 8);
      int r = f >> 3, c = (f & 7) << 2;
      *(float4*)&As[r][c] = *(const float4*)&A[(size_t)(bm + r) * D_MODEL + k0 + c];
      *(float4*)&Ws[r][c] = *(const float4*)&W[(size_t)(bn + r) * D_MODEL + k0 + c];
    }
    __syncthreads();
#pragma unroll
    for (int kk = 0; kk < 32; kk += 4) {
      float4 av[4], wv[4];
#pragma unroll
      for (int i = 0; i < 4; ++i) av[i] = *(const float4*)&As[ty * 4 + i][kk];
#pragma unroll
      for (int j = 0; j < 4; ++j) wv[j] = *(const float4*)&Ws[tx + 16 * j][kk];
#pragma unroll
      for (int i = 0; i < 4; ++i)
#pragma unroll
        for (int j = 0; j < 4; ++j)
          acc[i][j] += av[i].x * wv[j].x + av[i].y * wv[j].y +
                       av[i].z * wv[j].z + av[i].w * wv[j].w;
    }
  }

#pragma unroll
  for (int i = 0; i < 4; ++i) {
    int row = bm + ty * 4 + i;
#pragma unroll
    for (int j = 0; j < 4; ++j) {
      int col = bn + tx + 16 * j;
      float v = acc[i][j] + bias[col];
      size_t idx = (size_t)row * D_MODEL + col;
      C[idx] = v;
      if (Ch) {
        unsigned short hi = f2bf(v);
        Ch[idx] = hi;
        Cl[idx] = f2bf(v - bf2f(hi));
      }
    }
  }
}

// ---------------------------------------------------------------------------
// f32 GEMM (output projection, R15-proven 64x64 tile): C = A @ W.T + b
// ---------------------------------------------------------------------------
__global__ __launch_bounds__(256) void gemm_bias_kernel(
    const float* __restrict__ A, const float* __restrict__ W,
    const float* __restrict__ bias, float* __restrict__ C,
    int M, int N, int K)
{
  __shared__ float As[64][36];
  __shared__ float Ws[64][36];
  const int t  = threadIdx.x;
  const int tx = t & 15, ty = t >> 4;
  const int bm = blockIdx.y << 6, bn = blockIdx.x << 6;

  float acc[4][4] = {};

  for (int k0 = 0; k0 < K; k0 += 32) {
    __syncthreads();
#pragma unroll
    for (int i = 0; i < 2; ++i) {
      int f = t + (i << 8);
      int r = f >> 3, c = (f & 7) << 2;
      *(float4*)&As[r][c] = *(const float4*)&A[(size_t)(bm + r) * K + k0 + c];
      *(float4*)&Ws[r][c] = *(const float4*)&W[(size_t)(bn + r) * K + k0 + c];
    }
    __syncthreads();
#pragma unroll
    for (int kk = 0; kk < 32; kk += 4) {
      float4 av[4], wv[4];
#pragma unroll
      for (int i = 0; i < 4; ++i) av[i] = *(const float4*)&As[ty * 4 + i][kk];
#pragma unroll
      for (int j = 0; j < 4; ++j) wv[j] = *(const float4*)&Ws[tx + 16 * j][kk];
#pragma unroll
      for (int i = 0; i < 4; ++i)
#pragma unroll
        for (int j = 0; j < 4; ++j)
          acc[i][j] += av[i].x * wv[j].x + av[i].y * wv[j].y +
                       av[i].z * wv[j].z + av[i].w * wv[j].w;
    }
  }

#pragma unroll
  for (int i = 0; i < 4; ++i) {
    int row = bm + ty * 4 + i;
#pragma unroll
    for (int j = 0; j < 4; ++j) {
      int col = bn + tx + 16 * j;
      C[(size_t)row * N + col] = acc[i][j] + bias[col];
    }
  }
}

// ---------------------------------------------------------------------------
// Per-(b,h,e) max |K_e| over keys — feeds the provable error margin.
// ---------------------------------------------------------------------------
__global__ __launch_bounds__(256) void kemax_kernel(
    const float* __restrict__ Kf, float* __restrict__ kemax)
{
  const int bh = blockIdx.x;
  const int b = bh >> 3, h = bh & 7;
  const int e = threadIdx.x & 63, chunk = threadIdx.x >> 6;
  const float* base = Kf + ((size_t)b * SEQ_L) * D_MODEL + h * HEAD_E + e;
  float mx = 0.f;
  for (int k = chunk * 512; k < chunk * 512 + 512; ++k)
    mx = fmaxf(mx, fabsf(base[(size_t)k * D_MODEL]));
  __shared__ float red[4][64];
  red[chunk][e] = mx;
  __syncthreads();
  if (threadIdx.x < 64) {
    float m0 = fmaxf(fmaxf(red[0][threadIdx.x], red[1][threadIdx.x]),
                     fmaxf(red[2][threadIdx.x], red[3][threadIdx.x]));
    kemax[bh * 64 + threadIdx.x] = m0;
  }
}

// ---------------------------------------------------------------------------
// Main ProbSparse attention v16 — R15 structure with SPLIT-bf16 MFMA scan:
// score error <= red*5.7e-6 + f16store(1e-3), so margin shrinks to
// red*2e-5 + 0.004 => captured ~66 candidates (was ~181). Rescore is 2
// streams/lane (was 4), CCAP 128. All other machinery byte-identical.
// ---------------------------------------------------------------------------
__global__ __launch_bounds__(512) void attn_main(
    const float* __restrict__ Qf, const float* __restrict__ Kf,
    const float* __restrict__ Vf,
    const unsigned short* __restrict__ Qh, const unsigned short* __restrict__ Kh,
    const unsigned short* __restrict__ Qlo, const unsigned short* __restrict__ Klo,
    const float* __restrict__ kemax, float* __restrict__ AO,
    int* __restrict__ nflag, int* __restrict__ flagged)
{
  __shared__ __half  S[16][SP];          // 65600 B approx scores
  __shared__ short   cis2[8][CCAP];      // captured candidate indices
  __shared__ float   cvs[8][64];         // exact candidates (post bisect)
  __shared__ short   cis[8][64];
  __shared__ float   qrowL[16][64];      // f32 q rows (hoisted)
  __shared__ float   kemaxL[64];

  const int t    = threadIdx.x;
  const int w    = t >> 6;
  const int l    = t & 63;

  // XCD-affine decode
  const int wg   = blockIdx.x;
  const int xcd  = wg & 7;
  const int idx  = wg >> 3;
  const int bh   = xcd + 8 * (idx >> 7);
  const int qblk = idx & 127;
  const int b    = bh >> 3, h = bh & 7;
  const int q0   = qblk << 4;
  const size_t rowbase = (size_t)b * SEQ_L;

  if (t < 64) kemaxL[t] = kemax[bh * 64 + t];

  // hoist both q-row loads (latency overlaps the MFMA scan)
  {
    const float* qb = Qf + (rowbase + q0 + 2 * w) * D_MODEL + h * HEAD_E;
    qrowL[2 * w][l]     = qb[l];
    qrowL[2 * w + 1][l] = qb[D_MODEL + l];
  }

  // ---- split-bf16 MFMA score scan: wave w covers keys [w*256, w*256+256) ----
  {
    const int lo16 = l & 15, grp = l >> 4;
    const size_t qoff = (rowbase + q0 + lo16) * D_MODEL + h * HEAD_E;
    bf16x8 a0h = *(const bf16x8*)&Qh [qoff + grp * 8];
    bf16x8 a1h = *(const bf16x8*)&Qh [qoff + 32 + grp * 8];
    bf16x8 a0l = *(const bf16x8*)&Qlo[qoff + grp * 8];
    bf16x8 a1l = *(const bf16x8*)&Qlo[qoff + 32 + grp * 8];

    const int kbase = w * 256;
#pragma unroll
    for (int kt = 0; kt < 4; ++kt) {
#pragma unroll
      for (int kc = 0; kc < 4; ++kc) {
        const int key0 = kbase + kt * 64 + kc * 16 + lo16;
        const size_t koff = (rowbase + key0) * D_MODEL + h * HEAD_E;
        bf16x8 b0h = *(const bf16x8*)&Kh [koff + grp * 8];
        bf16x8 b1h = *(const bf16x8*)&Kh [koff + 32 + grp * 8];
        bf16x8 b0l = *(const bf16x8*)&Klo[koff + grp * 8];
        bf16x8 b1l = *(const bf16x8*)&Klo[koff + 32 + grp * 8];
        f32x4 acc = {0.f, 0.f, 0.f, 0.f};
        acc = __builtin_amdgcn_mfma_f32_16x16x32_bf16(a0l, b0h, acc, 0, 0, 0);
        acc = __builtin_amdgcn_mfma_f32_16x16x32_bf16(a0h, b0l, acc, 0, 0, 0);
        acc = __builtin_amdgcn_mfma_f32_16x16x32_bf16(a0h, b0h, acc, 0, 0, 0);
        acc = __builtin_amdgcn_mfma_f32_16x16x32_bf16(a1l, b1h, acc, 0, 0, 0);
        acc = __builtin_amdgcn_mfma_f32_16x16x32_bf16(a1h, b1l, acc, 0, 0, 0);
        acc = __builtin_amdgcn_mfma_f32_16x16x32_bf16(a1h, b1h, acc, 0, 0, 0);
#pragma unroll
        for (int r = 0; r < 4; ++r)
          S[grp * 4 + r][key0] = __float2half(acc[r] * 0.125f);
      }
    }
  }
  __syncthreads();

  // ---- selection: wave w handles queries 2w, 2w+1 ----
  for (int qq = 0; qq < 2; ++qq) {
    const int q   = 2 * w + qq;
    const int qid = bh * SEQ_L + q0 + q;

    float v[32];
#pragma unroll
    for (int j = 0; j < 32; ++j) v[j] = __half2float(S[q][(j << 6) + l]);

    // fused max / mean / var reduce
    float m = v[0], s1 = 0.f, s2 = 0.f;
#pragma unroll
    for (int j = 0; j < 32; ++j) {
      m = fmaxf(m, v[j]); s1 += v[j]; s2 += v[j] * v[j];
    }
#pragma unroll
    for (int off = 1; off < 64; off <<= 1) {
      m  = fmaxf(m, __shfl_xor(m, off));
      s1 += __shfl_xor(s1, off);
      s2 += __shfl_xor(s2, off);
    }
    const float mu = s1 * (1.0f / 2048.0f);
    const float sg = sqrtf(fmaxf(s2 * (1.0f / 2048.0f) - mu * mu, 0.f));
    const float lo = mu + 1.863f * sg;   // targets count ~ 64

    // ONE verify countge
    int C = 0;
#pragma unroll
    for (int j = 0; j < 32; ++j) C += (v[j] >= lo) ? 1 : 0;
#pragma unroll
    for (int off = 1; off < 64; off <<= 1) C += __shfl_xor(C, off);

    bool punt = (C < 40) | (C > 120);
    int base = 0;
    if (!punt) {
      // provable margin capture — split-bf16 error bound (1.8x slack)
      float red = fabsf(qrowL[q][l]) * kemaxL[l];
#pragma unroll
      for (int off = 1; off < 64; off <<= 1) red += __shfl_xor(red, off);
      const float lo2 = lo - (red * 2e-5f + 0.004f);
#pragma unroll
      for (int j = 0; j < 32; ++j) {
        bool in = (v[j] >= lo2);
        unsigned long long mk = __ballot(in);
        if (in) {
          int pos = base + (int)__popcll(mk & ((1ull << l) - 1ull));
          if (pos < CCAP) cis2[w][pos] = (short)((j << 6) | l);
        }
        base += (int)__popcll(mk);
      }
      punt = (base > CCAP);
    }
    if (punt) {
      if (l == 0) { int p = atomicAdd(nflag, 1); flagged[p] = qid; }
      continue;
    }

    // ---- exact f32 rescore of captured candidates (2 per lane) ----
    const int count2 = base;
    const int i0 = l, i1 = 64 + l;
    const int idx0 = (i0 < count2) ? (int)cis2[w][i0] : 0;
    const int idx1 = (i1 < count2) ? (int)cis2[w][i1] : 0;
    float e0 = -3.0e38f, e1 = -3.0e38f;
    {
      const float* kr0 = Kf + (rowbase + idx0) * D_MODEL + h * HEAD_E;
      const float* kr1 = Kf + (rowbase + idx1) * D_MODEL + h * HEAD_E;
      float r0 = 0.f, r1 = 0.f;
#pragma unroll
      for (int e4 = 0; e4 < 16; ++e4) {
        float4 qv = *(const float4*)&qrowL[q][e4 * 4];
        float4 k0 = *(const float4*)&kr0[e4 * 4];
        float4 k1 = *(const float4*)&kr1[e4 * 4];
        r0 += qv.x * k0.x + qv.y * k0.y + qv.z * k0.z + qv.w * k0.w;
        r1 += qv.x * k1.x + qv.y * k1.y + qv.z * k1.z + qv.w * k1.w;
      }
      if (i0 < count2) e0 = r0 * 0.125f;
      if (i1 < count2) e1 = r1 * 0.125f;
    }

    // exact bisect to count in [40, 64]
    float hiv = fmaxf(e0, e1);
    float lov = fminf((i0 < count2) ? e0 : 3.0e38f,
                      (i1 < count2) ? e1 : 3.0e38f);
#pragma unroll
    for (int off = 1; off < 64; off <<= 1) {
      hiv = fmaxf(hiv, __shfl_xor(hiv, off));
      lov = fminf(lov, __shfl_xor(lov, off));
    }
    lov -= 1e-3f;
    for (int it = 0; it < 30; ++it) {
      int c = (int)__popcll(__ballot(e0 >= lov)) +
              (int)__popcll(__ballot(e1 >= lov));
      if (c <= 64) break;
      float mid = 0.5f * (lov + hiv);
      int cm = (int)__popcll(__ballot(e0 >= mid)) +
               (int)__popcll(__ballot(e1 >= mid));
      if (cm >= 40) lov = mid; else hiv = mid;
    }

    // compact exact-selected into cvs/cis (key order preserved)
    int C2;
    {
      bool in0 = (e0 >= lov);
      bool in1 = (e1 >= lov);
      unsigned long long m0 = __ballot(in0);
      unsigned long long m1 = __ballot(in1);
      int tot0 = (int)__popcll(m0);
      if (in0) {
        int p = (int)__popcll(m0 & ((1ull << l) - 1ull));
        if (p < 64) { cvs[w][p] = e0; cis[w][p] = (short)idx0; }
      }
      if (in1) {
        int p = tot0 + (int)__popcll(m1 & ((1ull << l) - 1ull));
        if (p < 64) { cvs[w][p] = e1; cis[w][p] = (short)idx1; }
      }
      int tot = tot0 + (int)__popcll(m1);
      C2 = (tot < 64) ? tot : 64;
    }

    float cval = (l < C2) ? cvs[w][l] : -3.0e38f;
    int   cidx = (l < C2) ? (int)cis[w][l] : (2 * SEQ_L + l);

    // bitonic sort 64: value desc, index asc
#pragma unroll
    for (int sz = 2; sz <= 64; sz <<= 1) {
#pragma unroll
      for (int st = sz >> 1; st >= 1; st >>= 1) {
        float ov = __shfl_xor(cval, st);
        int   oi = __shfl_xor(cidx, st);
        bool ob    = (ov > cval) || ((ov == cval) && (oi < cidx));
        bool dir   = ((l & sz) == 0);
        bool lower = ((l & st) == 0);
        if (ob == (lower == dir)) { cval = ov; cidx = oi; }
      }
    }

    const float m_ex = __shfl(cval, 0);
    const float v37  = __shfl(cval, 37);
    const float v38  = __shfl(cval, 38);
    if (v37 - v38 < 2e-5f) {           // tight boundary -> fixup
      if (l == 0) { int p = atomicAdd(nflag, 1); flagged[p] = qid; }
      continue;
    }

    float myw = (l < KSEL) ? __expf(cval - m_ex) : 0.f;
    float psum = myw;
#pragma unroll
    for (int off = 1; off < 64; off <<= 1) psum += __shfl_xor(psum, off);
    const float inv = 1.0f / psum;

    // ---- PV: branchless, 8 gather loads in flight per batch ----
    const float* Vb = Vf + rowbase * D_MODEL + h * HEAD_E;
    float acc = 0.f;
    for (int j0 = 0; j0 < 40; j0 += 8) {
      float wv8[8]; const float* vp8[8];
#pragma unroll
      for (int u = 0; u < 8; ++u) {
        wv8[u] = __shfl(myw, j0 + u);
        int sj = __shfl(cidx, j0 + u) & (SEQ_L - 1);
        vp8[u] = Vb + (size_t)sj * D_MODEL + l;
      }
      float vv8[8];
#pragma unroll
      for (int u = 0; u < 8; ++u) vv8[u] = *vp8[u];
#pragma unroll
      for (int u = 0; u < 8; ++u) acc = fmaf(wv8[u], vv8[u], acc);
    }
    AO[(rowbase + q0 + q) * D_MODEL + h * HEAD_E + l] = acc * inv;
  }
}

// ---------------------------------------------------------------------------
// Fixup: 8-wave cooperative per query (unchanged, proven).
// ---------------------------------------------------------------------------
__global__ __launch_bounds__(512) void attn_fixup(
    const float* __restrict__ Qf, const float* __restrict__ Kf,
    const float* __restrict__ Vf,
    const float* __restrict__ x,
    const float* __restrict__ Wq, const float* __restrict__ bq,
    const float* __restrict__ Wk, const float* __restrict__ bk,
    float* __restrict__ AO,
    const int* __restrict__ nflag, const int* __restrict__ flagged)
{
  __shared__ float  Kt[8][2048];    // per-wave swizzled 32-key tile, 8 x 8 KB
  __shared__ float  Sf[SEQ_L];      // exact f32 scores, 8 KB
  __shared__ float  qr[64];
  __shared__ double qdL[64];
  __shared__ double uL[512];
  __shared__ double dL[64];
  __shared__ int    ciL[64];
  __shared__ int    C2s;

  const int t = threadIdx.x;
  const int w = t >> 6;
  const int l = t & 63;
  const int n = *nflag;

  for (int s = blockIdx.x; s < n; s += gridDim.x) {
    const int qid  = flagged[s];
    const int bh   = qid >> 11, qrow = qid & (SEQ_L - 1);
    const int b    = bh >> 3, h = bh & 7;
    const size_t rowbase = (size_t)b * SEQ_L;
    const float* Kb = Kf + rowbase * D_MODEL + h * HEAD_E;
    const float* xr = x + (rowbase + qrow) * D_MODEL;

    if (t < 64) qr[t] = Qf[(rowbase + qrow) * D_MODEL + h * HEAD_E + t];
    float xreg[8];
#pragma unroll
    for (int jc = 0; jc < 8; ++jc) xreg[jc] = xr[(jc << 6) + l];
    __syncthreads();

    // lane's dim-half Q fragments
    const int hf = l >> 5, k32 = l & 31;
    float4 q_r[8];
#pragma unroll
    for (int i = 0; i < 8; ++i) q_r[i] = *(const float4*)&qr[(hf * 8 + i) * 4];

    float* Ktw = &Kt[w][0];

    // ---- exact f32 K-scan: wave w owns keys [256w, 256w+256), 8 tiles of 32 ----
    for (int ti = 0; ti < 8; ++ti) {
      const int kbase = w * 256 + ti * 32;
      __syncthreads();                         // uniform; guards Ktw reuse
#pragma unroll
      for (int i = 0; i < 8; ++i) {
        int f = (i << 6) + l;                  // 512 float4 slots (32 rows x 16)
        int r = f >> 4, c4 = f & 15;
        ((float4*)Ktw)[(r << 4) | (c4 ^ (r & 15))] =
            *(const float4*)&Kb[(size_t)(kbase + r) * D_MODEL + (c4 << 2)];
      }
      __syncthreads();
      float p0 = 0.f, p1 = 0.f;
#pragma unroll
      for (int i = 0; i < 8; i += 2) {
        int e4a = hf * 8 + i, e4b = e4a + 1;
        float4 ka = ((const float4*)Ktw)[(k32 << 4) | (e4a ^ (k32 & 15))];
        float4 kb = ((const float4*)Ktw)[(k32 << 4) | (e4b ^ (k32 & 15))];
        p0 += q_r[i].x*ka.x + q_r[i].y*ka.y + q_r[i].z*ka.z + q_r[i].w*ka.w;
        p1 += q_r[i+1].x*kb.x + q_r[i+1].y*kb.y + q_r[i+1].z*kb.z + q_r[i+1].w*kb.w;
      }
      float p = p0 + p1;
      p += __shfl_xor(p, 32);                  // combine dim-halves
      if (l < 32) Sf[kbase + k32] = p * 0.125f;
    }
    __syncthreads();

    // ---- qd phase: wave w computes qdL[8w .. 8w+8) ----
    for (int sub = 0; sub < 8; ++sub) {
      const int he = w * 8 + sub;
      const float* wqr = Wq + (size_t)(h * HEAD_E + he) * D_MODEL;
      double p = 0.0;
#pragma unroll
      for (int jc = 0; jc < 8; ++jc)
        p += (double)wqr[(jc << 6) + l] * (double)xreg[jc];
#pragma unroll
      for (int off = 1; off < 64; off <<= 1) p += __shfl_xor(p, off);
      if (l == 0) qdL[he] = p + (double)bq[h * HEAD_E + he];
    }
    __syncthreads();                            // qdL complete

    // ---- u phase: thread t owns j=t; coalesced column accumulate ----
    {
      double u = 0.0;
#pragma unroll 8
      for (int e = 0; e < 64; ++e)
        u += qdL[e] * (double)Wk[(size_t)(h * HEAD_E + e) * D_MODEL + t];
      uL[t] = u;
    }

    // ---- selection on wave 0 (bisect + compact, from Sf) ----
    if (w == 0) {
      float v[32];
#pragma unroll
      for (int j = 0; j < 32; ++j) v[j] = Sf[(j << 6) + l];

      float hiv = v[0], lov = v[0];
#pragma unroll
      for (int j = 1; j < 32; ++j) { hiv = fmaxf(hiv, v[j]); lov = fminf(lov, v[j]); }
#pragma unroll
      for (int off = 1; off < 64; off <<= 1) {
        hiv = fmaxf(hiv, __shfl_xor(hiv, off));
        lov = fminf(lov, __shfl_xor(lov, off));
      }
      lov -= 1e-3f;
      for (int it = 0; it < 30; ++it) {
        int c = 0;
#pragma unroll
        for (int j = 0; j < 32; ++j) c += (v[j] >= lov) ? 1 : 0;
#pragma unroll
        for (int off = 1; off < 64; off <<= 1) c += __shfl_xor(c, off);
        if (c <= 64) break;
        float mid = 0.5f * (lov + hiv);
        int cm = 0;
#pragma unroll
        for (int j = 0; j < 32; ++j) cm += (v[j] >= mid) ? 1 : 0;
#pragma unroll
        for (int off = 1; off < 64; off <<= 1) cm += __shfl_xor(cm, off);
        if (cm >= 40) lov = mid; else hiv = mid;
      }

      int bb = 0;
#pragma unroll
      for (int j = 0; j < 32; ++j) {
        bool in = (v[j] >= lov);
        unsigned long long mk = __ballot(in);
        if (in) {
          int pos = bb + (int)__popcll(mk & ((1ull << l) - 1ull));
          if (pos < 64) ciL[pos] = (j << 6) + l;
        }
        bb += (int)__popcll(mk);
      }
      if (l == 0) C2s = (bb < 64) ? bb : 64;
    }
    __syncthreads();                            // uL, ciL, C2s complete

    const int C2 = C2s;

    // qkb (per wave, from qdL)
    double qkb = qdL[l] * (double)bk[h * HEAD_E + l];
#pragma unroll
    for (int off = 1; off < 64; off <<= 1) qkb += __shfl_xor(qkb, off);

    // ---- s_c phase: wave w owns candidates 8w .. 8w+8 ----
    for (int sub = 0; sub < 8; ++sub) {
      const int c = w * 8 + sub;
      const int row = (c < C2) ? ciL[c] : 0;
      const float* xc = x + (rowbase + row) * D_MODEL + l;
      double p = 0.0;
#pragma unroll
      for (int jc = 0; jc < 8; ++jc)
        p += uL[(jc << 6) + l] * (double)xc[jc << 6];
#pragma unroll
      for (int off = 1; off < 64; off <<= 1) p += __shfl_xor(p, off);
      if (l == 0) dL[c] = (c < C2) ? (qkb + p) * 0.125 : -1.0e300;
    }
    __syncthreads();                            // dL complete

    // ---- rank / softmax / PV on wave 0 ----
    if (w == 0) {
      double d = dL[l];
      int myi = (l < C2) ? ciL[l] : (2 * SEQ_L + l);
      double mxd = -1.0e300; int rank = 0;
      for (int j = 0; j < 64; ++j) {
        double dj = dL[j];
        int    ij = (j < C2) ? ciL[j] : (2 * SEQ_L + j);
        if (dj > mxd) mxd = dj;
        rank += (dj > d) || ((dj == d) && (ij < myi));
      }
      float myw = (l < C2 && rank < KSEL) ? __expf((float)(d - mxd)) : 0.f;

      float psum = myw;
#pragma unroll
      for (int off = 1; off < 64; off <<= 1) psum += __shfl_xor(psum, off);
      const float inv = 1.0f / psum;

      const float* Vb = Vf + rowbase * D_MODEL + h * HEAD_E;
      float acc = 0.f;
      for (int j0 = 0; j0 < 64; j0 += 8) {
        float wv8[8]; const float* vp8[8];
#pragma unroll
        for (int u8 = 0; u8 < 8; ++u8) {
          wv8[u8] = __shfl(myw, j0 + u8);
          int sj = __shfl(myi, j0 + u8) & (SEQ_L - 1);
          vp8[u8] = Vb + (size_t)sj * D_MODEL + l;
        }
        float vv8[8];
#pragma unroll
        for (int u8 = 0; u8 < 8; ++u8) vv8[u8] = *vp8[u8];
#pragma unroll
        for (int u8 = 0; u8 < 8; ++u8) acc = fmaf(wv8[u8], vv8[u8], acc);
      }
      AO[(rowbase + qrow) * D_MODEL + h * HEAD_E + l] = acc * inv;
    }
    __syncthreads();                            // protect LDS before next query
  }
}

// ---------------------------------------------------------------------------
extern "C" void kernel_launch(void* const* d_in, const int* in_sizes, int n_in,
                              void* d_out, int out_size, void* d_ws, size_t ws_size,
                              hipStream_t stream) {
  const float* x  = (const float*)d_in[0];
  const float* Wq = (const float*)d_in[1];
  const float* bq = (const float*)d_in[2];
  const float* Wk = (const float*)d_in[3];
  const float* bk = (const float*)d_in[4];
  const float* Wv = (const float*)d_in[5];
  const float* bv = (const float*)d_in[6];
  const float* Wo = (const float*)d_in[7];
  const float* bo = (const float*)d_in[8];
  float* out = (float*)d_out;

  char* ws = (char*)d_ws;
  const size_t MATB = (size_t)M_ROWS * D_MODEL * 4;  // 8 MB
  float* Qf = (float*)ws;
  float* Kf = (float*)(ws + MATB);
  float* Vf = (float*)(ws + 2 * MATB);
  float* AO = (float*)(ws + 3 * MATB);
  unsigned short* Qh  = (unsigned short*)(ws + 4 * MATB);                // 4 MB
  unsigned short* Kh  = (unsigned short*)(ws + 4 * MATB + MATB / 2);     // 4 MB
  unsigned short* Qlo = (unsigned short*)(ws + 5 * MATB);                // 4 MB
  unsigned short* Klo = (unsigned short*)(ws + 5 * MATB + MATB / 2);     // 4 MB
  float* kemax = (float*)(ws + 6 * MATB);                                // 4 KB
  int* nflag   = (int*)(ws + 6 * MATB + 4096);
  int* flagged = (int*)(ws + 6 * MATB + 8192);                           // 128 KB

  hipMemsetAsync(nflag, 0, 64, stream);

  dim3 qkvgrid(D_MODEL / 64, M_ROWS / 64, 3);   // (8, 64, 3)
  gemm_qkv_kernel<<<qkvgrid, 256, 0, stream>>>(
      x, Wq, bq, Wk, bk, Wv, bv, Qf, Kf, Vf, Qh, Kh, Qlo, Klo);

  kemax_kernel<<<dim3(BATCH * N_HEADS), 256, 0, stream>>>(Kf, kemax);

  attn_main<<<dim3(SEQ_L / 16 * BATCH * N_HEADS), 512, 0, stream>>>(
      Qf, Kf, Vf, Qh, Kh, Qlo, Klo, kemax, AO, nflag, flagged);

  attn_fixup<<<dim3(1024), 512, 0, stream>>>(
      Qf, Kf, Vf, x, Wq, bq, Wk, bk, AO, nflag, flagged);

  dim3 ggrid(D_MODEL / 64, M_ROWS / 64);        // (8, 64)
  gemm_bias_kernel<<<ggrid, 256, 0, stream>>>(AO, Wo, bo, out, M_ROWS, D_MODEL, D_MODEL);
}

// Round 19
// 607.116 us; speedup vs baseline: 1.5719x; 1.0856x over previous
//
#include <hip/hip_runtime.h>
#include <hip/hip_fp16.h>
#include <cstdint>
#include <cstddef>

#define D_MODEL 512
#define N_HEADS 8
#define HEAD_E  64
#define SEQ_L   2048
#define BATCH   2
#define KSEL    38            // int(5*log(2048)) = 38
#define M_ROWS  (BATCH*SEQ_L) // 4096
#define SP      2050          // S row stride (f16)
#define CCAP    128           // candidate cap (2 per lane); overflow -> fixup
#define FSLOTS  4096          // candbuf slots

typedef short bf16x8 __attribute__((ext_vector_type(8)));
typedef float f32x4  __attribute__((ext_vector_type(4)));

static __device__ __forceinline__ unsigned short f2bf(float x) {
  uint32_t u = __float_as_uint(x);
  return (unsigned short)((u + 0x7FFF + ((u >> 16) & 1)) >> 16);  // RNE
}
static __device__ __forceinline__ float bf2f(unsigned short h) {
  return __uint_as_float((uint32_t)h << 16);
}

// ---------------------------------------------------------------------------
// Fused QKV f32 GEMM (64x64 tile): z=0:Q, z=1:K, z=2:V. C = x @ W.T + b.
// Q,K also emit split-bf16 (hi + lo residual) copies.
// ---------------------------------------------------------------------------
__global__ __launch_bounds__(256) void gemm_qkv_kernel(
    const float* __restrict__ A,
    const float* __restrict__ Wq, const float* __restrict__ bq,
    const float* __restrict__ Wk, const float* __restrict__ bk,
    const float* __restrict__ Wv, const float* __restrict__ bv,
    float* __restrict__ Qf, float* __restrict__ Kf, float* __restrict__ Vf,
    unsigned short* __restrict__ Qh, unsigned short* __restrict__ Kh,
    unsigned short* __restrict__ Qlo, unsigned short* __restrict__ Klo)
{
  const int z = blockIdx.z;
  const float* W    = (z == 0) ? Wq : ((z == 1) ? Wk : Wv);
  const float* bias = (z == 0) ? bq : ((z == 1) ? bk : bv);
  float* C          = (z == 0) ? Qf : ((z == 1) ? Kf : Vf);
  unsigned short* Ch = (z == 0) ? Qh : ((z == 1) ? Kh : nullptr);
  unsigned short* Cl = (z == 0) ? Qlo : ((z == 1) ? Klo : nullptr);

  __shared__ float As[64][36];
  __shared__ float Ws[64][36];
  const int t  = threadIdx.x;
  const int tx = t & 15, ty = t >> 4;
  const int bm = blockIdx.y << 6, bn = blockIdx.x << 6;

  float acc[4][4] = {};

  for (int k0 = 0; k0 < D_MODEL; k0 += 32) {
    __syncthreads();
#pragma unroll
    for (int i = 0; i < 2; ++i) {
      int f = t + (i << 8);
      int r = f >> 3, c = (f & 7) << 2;
      *(float4*)&As[r][c] = *(const float4*)&A[(size_t)(bm + r) * D_MODEL + k0 + c];
      *(float4*)&Ws[r][c] = *(const float4*)&W[(size_t)(bn + r) * D_MODEL + k0 + c];
    }
    __syncthreads();
#pragma unroll
    for (int kk = 0; kk < 32; kk += 4) {
      float4 av[4], wv[4];
#pragma unroll
      for (int i = 0; i < 4; ++i) av[i] = *(const float4*)&As[ty * 4 + i][kk];
#pragma unroll
      for (int j = 0; j < 4; ++j) wv[j] = *(const float4*)&Ws[tx + 16 * j][kk];
#pragma unroll
      for (int i = 0; i < 4; ++i)
#pragma unroll
        for (int j = 0; j < 4; ++j)
          acc[i][j] += av[i].x * wv[j].x + av[i].y * wv[j].y +
                       av[i].z * wv[j].z + av[i].w * wv[j].w;
    }
  }

#pragma unroll
  for (int i = 0; i < 4; ++i) {
    int row = bm + ty * 4 + i;
#pragma unroll
    for (int j = 0; j < 4; ++j) {
      int col = bn + tx + 16 * j;
      float v = acc[i][j] + bias[col];
      size_t idx = (size_t)row * D_MODEL + col;
      C[idx] = v;
      if (Ch) {
        unsigned short hi = f2bf(v);
        Ch[idx] = hi;
        Cl[idx] = f2bf(v - bf2f(hi));
      }
    }
  }
}

// ---------------------------------------------------------------------------
// f32 GEMM (output projection, 64x64 tile): C = A @ W.T + b
// ---------------------------------------------------------------------------
__global__ __launch_bounds__(256) void gemm_bias_kernel(
    const float* __restrict__ A, const float* __restrict__ W,
    const float* __restrict__ bias, float* __restrict__ C,
    int M, int N, int K)
{
  __shared__ float As[64][36];
  __shared__ float Ws[64][36];
  const int t  = threadIdx.x;
  const int tx = t & 15, ty = t >> 4;
  const int bm = blockIdx.y << 6, bn = blockIdx.x << 6;

  float acc[4][4] = {};

  for (int k0 = 0; k0 < K; k0 += 32) {
    __syncthreads();
#pragma unroll
    for (int i = 0; i < 2; ++i) {
      int f = t + (i << 8);
      int r = f >> 3, c = (f & 7) << 2;
      *(float4*)&As[r][c] = *(const float4*)&A[(size_t)(bm + r) * K + k0 + c];
      *(float4*)&Ws[r][c] = *(const float4*)&W[(size_t)(bn + r) * K + k0 + c];
    }
    __syncthreads();
#pragma unroll
    for (int kk = 0; kk < 32; kk += 4) {
      float4 av[4], wv[4];
#pragma unroll
      for (int i = 0; i < 4; ++i) av[i] = *(const float4*)&As[ty * 4 + i][kk];
#pragma unroll
      for (int j = 0; j < 4; ++j) wv[j] = *(const float4*)&Ws[tx + 16 * j][kk];
#pragma unroll
      for (int i = 0; i < 4; ++i)
#pragma unroll
        for (int j = 0; j < 4; ++j)
          acc[i][j] += av[i].x * wv[j].x + av[i].y * wv[j].y +
                       av[i].z * wv[j].z + av[i].w * wv[j].w;
    }
  }

#pragma unroll
  for (int i = 0; i < 4; ++i) {
    int row = bm + ty * 4 + i;
#pragma unroll
    for (int j = 0; j < 4; ++j) {
      int col = bn + tx + 16 * j;
      C[(size_t)row * N + col] = acc[i][j] + bias[col];
    }
  }
}

// ---------------------------------------------------------------------------
// Per-(b,h,e) max |K_e| over keys — feeds the provable error margin.
// ---------------------------------------------------------------------------
__global__ __launch_bounds__(256) void kemax_kernel(
    const float* __restrict__ Kf, float* __restrict__ kemax)
{
  const int bh = blockIdx.x;
  const int b = bh >> 3, h = bh & 7;
  const int e = threadIdx.x & 63, chunk = threadIdx.x >> 6;
  const float* base = Kf + ((size_t)b * SEQ_L) * D_MODEL + h * HEAD_E + e;
  float mx = 0.f;
  for (int k = chunk * 512; k < chunk * 512 + 512; ++k)
    mx = fmaxf(mx, fabsf(base[(size_t)k * D_MODEL]));
  __shared__ float red[4][64];
  red[chunk][e] = mx;
  __syncthreads();
  if (threadIdx.x < 64) {
    float m0 = fmaxf(fmaxf(red[0][threadIdx.x], red[1][threadIdx.x]),
                     fmaxf(red[2][threadIdx.x], red[3][threadIdx.x]));
    kemax[bh * 64 + threadIdx.x] = m0;
  }
}

// ---------------------------------------------------------------------------
// Main ProbSparse attention v17 — R18 structure (split-bf16 scan, CCAP 128);
// tight-gap punts now EXPORT their sorted candidate set (candbuf + C2,
// flag bit 30) so the fixup can skip its 512 KB/query K-scan.
// ---------------------------------------------------------------------------
__global__ __launch_bounds__(512) void attn_main(
    const float* __restrict__ Qf, const float* __restrict__ Kf,
    const float* __restrict__ Vf,
    const unsigned short* __restrict__ Qh, const unsigned short* __restrict__ Kh,
    const unsigned short* __restrict__ Qlo, const unsigned short* __restrict__ Klo,
    const float* __restrict__ kemax, float* __restrict__ AO,
    int* __restrict__ nflag, int* __restrict__ flagged,
    short* __restrict__ candbuf, int* __restrict__ candC2)
{
  __shared__ __half  S[16][SP];          // 65600 B approx scores
  __shared__ short   cis2[8][CCAP];      // captured candidate indices
  __shared__ float   cvs[8][64];         // exact candidates (post bisect)
  __shared__ short   cis[8][64];
  __shared__ float   qrowL[16][64];      // f32 q rows (hoisted)
  __shared__ float   kemaxL[64];

  const int t    = threadIdx.x;
  const int w    = t >> 6;
  const int l    = t & 63;

  // XCD-affine decode
  const int wg   = blockIdx.x;
  const int xcd  = wg & 7;
  const int idx  = wg >> 3;
  const int bh   = xcd + 8 * (idx >> 7);
  const int qblk = idx & 127;
  const int b    = bh >> 3, h = bh & 7;
  const int q0   = qblk << 4;
  const size_t rowbase = (size_t)b * SEQ_L;

  if (t < 64) kemaxL[t] = kemax[bh * 64 + t];

  // hoist both q-row loads (latency overlaps the MFMA scan)
  {
    const float* qb = Qf + (rowbase + q0 + 2 * w) * D_MODEL + h * HEAD_E;
    qrowL[2 * w][l]     = qb[l];
    qrowL[2 * w + 1][l] = qb[D_MODEL + l];
  }

  // ---- split-bf16 MFMA score scan: wave w covers keys [w*256, w*256+256) ----
  {
    const int lo16 = l & 15, grp = l >> 4;
    const size_t qoff = (rowbase + q0 + lo16) * D_MODEL + h * HEAD_E;
    bf16x8 a0h = *(const bf16x8*)&Qh [qoff + grp * 8];
    bf16x8 a1h = *(const bf16x8*)&Qh [qoff + 32 + grp * 8];
    bf16x8 a0l = *(const bf16x8*)&Qlo[qoff + grp * 8];
    bf16x8 a1l = *(const bf16x8*)&Qlo[qoff + 32 + grp * 8];

    const int kbase = w * 256;
#pragma unroll
    for (int kt = 0; kt < 4; ++kt) {
#pragma unroll
      for (int kc = 0; kc < 4; ++kc) {
        const int key0 = kbase + kt * 64 + kc * 16 + lo16;
        const size_t koff = (rowbase + key0) * D_MODEL + h * HEAD_E;
        bf16x8 b0h = *(const bf16x8*)&Kh [koff + grp * 8];
        bf16x8 b1h = *(const bf16x8*)&Kh [koff + 32 + grp * 8];
        bf16x8 b0l = *(const bf16x8*)&Klo[koff + grp * 8];
        bf16x8 b1l = *(const bf16x8*)&Klo[koff + 32 + grp * 8];
        f32x4 acc = {0.f, 0.f, 0.f, 0.f};
        acc = __builtin_amdgcn_mfma_f32_16x16x32_bf16(a0l, b0h, acc, 0, 0, 0);
        acc = __builtin_amdgcn_mfma_f32_16x16x32_bf16(a0h, b0l, acc, 0, 0, 0);
        acc = __builtin_amdgcn_mfma_f32_16x16x32_bf16(a0h, b0h, acc, 0, 0, 0);
        acc = __builtin_amdgcn_mfma_f32_16x16x32_bf16(a1l, b1h, acc, 0, 0, 0);
        acc = __builtin_amdgcn_mfma_f32_16x16x32_bf16(a1h, b1l, acc, 0, 0, 0);
        acc = __builtin_amdgcn_mfma_f32_16x16x32_bf16(a1h, b1h, acc, 0, 0, 0);
#pragma unroll
        for (int r = 0; r < 4; ++r)
          S[grp * 4 + r][key0] = __float2half(acc[r] * 0.125f);
      }
    }
  }
  __syncthreads();

  // ---- selection: wave w handles queries 2w, 2w+1 ----
  for (int qq = 0; qq < 2; ++qq) {
    const int q   = 2 * w + qq;
    const int qid = bh * SEQ_L + q0 + q;

    float v[32];
#pragma unroll
    for (int j = 0; j < 32; ++j) v[j] = __half2float(S[q][(j << 6) + l]);

    // fused max / mean / var reduce
    float m = v[0], s1 = 0.f, s2 = 0.f;
#pragma unroll
    for (int j = 0; j < 32; ++j) {
      m = fmaxf(m, v[j]); s1 += v[j]; s2 += v[j] * v[j];
    }
#pragma unroll
    for (int off = 1; off < 64; off <<= 1) {
      m  = fmaxf(m, __shfl_xor(m, off));
      s1 += __shfl_xor(s1, off);
      s2 += __shfl_xor(s2, off);
    }
    const float mu = s1 * (1.0f / 2048.0f);
    const float sg = sqrtf(fmaxf(s2 * (1.0f / 2048.0f) - mu * mu, 0.f));
    const float lo = mu + 1.863f * sg;   // targets count ~ 64

    // ONE verify countge
    int C = 0;
#pragma unroll
    for (int j = 0; j < 32; ++j) C += (v[j] >= lo) ? 1 : 0;
#pragma unroll
    for (int off = 1; off < 64; off <<= 1) C += __shfl_xor(C, off);

    bool punt = (C < 40) | (C > 120);
    int base = 0;
    if (!punt) {
      // provable margin capture — split-bf16 error bound (1.8x slack)
      float red = fabsf(qrowL[q][l]) * kemaxL[l];
#pragma unroll
      for (int off = 1; off < 64; off <<= 1) red += __shfl_xor(red, off);
      const float lo2 = lo - (red * 2e-5f + 0.004f);
#pragma unroll
      for (int j = 0; j < 32; ++j) {
        bool in = (v[j] >= lo2);
        unsigned long long mk = __ballot(in);
        if (in) {
          int pos = base + (int)__popcll(mk & ((1ull << l) - 1ull));
          if (pos < CCAP) cis2[w][pos] = (short)((j << 6) | l);
        }
        base += (int)__popcll(mk);
      }
      punt = (base > CCAP);
    }
    if (punt) {
      if (l == 0) { int p = atomicAdd(nflag, 1); flagged[p] = qid; }
      continue;
    }

    // ---- exact f32 rescore of captured candidates (2 per lane) ----
    const int count2 = base;
    const int i0 = l, i1 = 64 + l;
    const int idx0 = (i0 < count2) ? (int)cis2[w][i0] : 0;
    const int idx1 = (i1 < count2) ? (int)cis2[w][i1] : 0;
    float e0 = -3.0e38f, e1 = -3.0e38f;
    {
      const float* kr0 = Kf + (rowbase + idx0) * D_MODEL + h * HEAD_E;
      const float* kr1 = Kf + (rowbase + idx1) * D_MODEL + h * HEAD_E;
      float r0 = 0.f, r1 = 0.f;
#pragma unroll
      for (int e4 = 0; e4 < 16; ++e4) {
        float4 qv = *(const float4*)&qrowL[q][e4 * 4];
        float4 k0 = *(const float4*)&kr0[e4 * 4];
        float4 k1 = *(const float4*)&kr1[e4 * 4];
        r0 += qv.x * k0.x + qv.y * k0.y + qv.z * k0.z + qv.w * k0.w;
        r1 += qv.x * k1.x + qv.y * k1.y + qv.z * k1.z + qv.w * k1.w;
      }
      if (i0 < count2) e0 = r0 * 0.125f;
      if (i1 < count2) e1 = r1 * 0.125f;
    }

    // exact bisect to count in [40, 64]
    float hiv = fmaxf(e0, e1);
    float lov = fminf((i0 < count2) ? e0 : 3.0e38f,
                      (i1 < count2) ? e1 : 3.0e38f);
#pragma unroll
    for (int off = 1; off < 64; off <<= 1) {
      hiv = fmaxf(hiv, __shfl_xor(hiv, off));
      lov = fminf(lov, __shfl_xor(lov, off));
    }
    lov -= 1e-3f;
    for (int it = 0; it < 30; ++it) {
      int c = (int)__popcll(__ballot(e0 >= lov)) +
              (int)__popcll(__ballot(e1 >= lov));
      if (c <= 64) break;
      float mid = 0.5f * (lov + hiv);
      int cm = (int)__popcll(__ballot(e0 >= mid)) +
               (int)__popcll(__ballot(e1 >= mid));
      if (cm >= 40) lov = mid; else hiv = mid;
    }

    // compact exact-selected into cvs/cis (key order preserved)
    int C2;
    {
      bool in0 = (e0 >= lov);
      bool in1 = (e1 >= lov);
      unsigned long long m0 = __ballot(in0);
      unsigned long long m1 = __ballot(in1);
      int tot0 = (int)__popcll(m0);
      if (in0) {
        int p = (int)__popcll(m0 & ((1ull << l) - 1ull));
        if (p < 64) { cvs[w][p] = e0; cis[w][p] = (short)idx0; }
      }
      if (in1) {
        int p = tot0 + (int)__popcll(m1 & ((1ull << l) - 1ull));
        if (p < 64) { cvs[w][p] = e1; cis[w][p] = (short)idx1; }
      }
      int tot = tot0 + (int)__popcll(m1);
      C2 = (tot < 64) ? tot : 64;
    }

    float cval = (l < C2) ? cvs[w][l] : -3.0e38f;
    int   cidx = (l < C2) ? (int)cis[w][l] : (2 * SEQ_L + l);

    // bitonic sort 64: value desc, index asc
#pragma unroll
    for (int sz = 2; sz <= 64; sz <<= 1) {
#pragma unroll
      for (int st = sz >> 1; st >= 1; st >>= 1) {
        float ov = __shfl_xor(cval, st);
        int   oi = __shfl_xor(cidx, st);
        bool ob    = (ov > cval) || ((ov == cval) && (oi < cidx));
        bool dir   = ((l & sz) == 0);
        bool lower = ((l & st) == 0);
        if (ob == (lower == dir)) { cval = ov; cidx = oi; }
      }
    }

    const float m_ex = __shfl(cval, 0);
    const float v37  = __shfl(cval, 37);
    const float v38  = __shfl(cval, 38);
    if (v37 - v38 < 2e-5f) {           // tight boundary -> fixup w/ candidates
      int p = 0;
      if (l == 0) p = atomicAdd(nflag, 1);
      p = __shfl(p, 0);
      if (p < FSLOTS) {
        candbuf[(size_t)p * 64 + l] = (short)cidx;  // sorted candidate set
        if (l == 0) { candC2[p] = C2; flagged[p] = qid | (1 << 30); }
      } else {
        if (l == 0) flagged[p] = qid;               // fallback: full fixup
      }
      continue;
    }

    float myw = (l < KSEL) ? __expf(cval - m_ex) : 0.f;
    float psum = myw;
#pragma unroll
    for (int off = 1; off < 64; off <<= 1) psum += __shfl_xor(psum, off);
    const float inv = 1.0f / psum;

    // ---- PV: branchless, 8 gather loads in flight per batch ----
    const float* Vb = Vf + rowbase * D_MODEL + h * HEAD_E;
    float acc = 0.f;
    for (int j0 = 0; j0 < 40; j0 += 8) {
      float wv8[8]; const float* vp8[8];
#pragma unroll
      for (int u = 0; u < 8; ++u) {
        wv8[u] = __shfl(myw, j0 + u);
        int sj = __shfl(cidx, j0 + u) & (SEQ_L - 1);
        vp8[u] = Vb + (size_t)sj * D_MODEL + l;
      }
      float vv8[8];
#pragma unroll
      for (int u = 0; u < 8; ++u) vv8[u] = *vp8[u];
#pragma unroll
      for (int u = 0; u < 8; ++u) acc = fmaf(wv8[u], vv8[u], acc);
    }
    AO[(rowbase + q0 + q) * D_MODEL + h * HEAD_E + l] = acc * inv;
  }
}

// ---------------------------------------------------------------------------
// Fixup v4: 8-wave cooperative per query. Tight-gap flags (bit 30) carry
// their candidate set -> skip K-scan + selection (the 512 KB/query fetch).
// Count-window flags keep the full-scan path. f64 math unchanged (proven).
// ---------------------------------------------------------------------------
__global__ __launch_bounds__(512) void attn_fixup(
    const float* __restrict__ Qf, const float* __restrict__ Kf,
    const float* __restrict__ Vf,
    const float* __restrict__ x,
    const float* __restrict__ Wq, const float* __restrict__ bq,
    const float* __restrict__ Wk, const float* __restrict__ bk,
    float* __restrict__ AO,
    const int* __restrict__ nflag, const int* __restrict__ flagged,
    const short* __restrict__ candbuf, const int* __restrict__ candC2)
{
  __shared__ float  Kt[8][2048];    // per-wave swizzled 32-key tile, 8 x 8 KB
  __shared__ float  Sf[SEQ_L];      // exact f32 scores, 8 KB
  __shared__ float  qr[64];
  __shared__ double qdL[64];
  __shared__ double uL[512];
  __shared__ double dL[64];
  __shared__ int    ciL[64];
  __shared__ int    C2s;

  const int t = threadIdx.x;
  const int w = t >> 6;
  const int l = t & 63;
  const int n = *nflag;

  for (int s = blockIdx.x; s < n; s += gridDim.x) {
    const int fq   = flagged[s];
    const bool tight = (fq & (1 << 30)) != 0;
    const int qid  = fq & 0x3FFFFFFF;
    const int bh   = qid >> 11, qrow = qid & (SEQ_L - 1);
    const int b    = bh >> 3, h = bh & 7;
    const size_t rowbase = (size_t)b * SEQ_L;
    const float* Kb = Kf + rowbase * D_MODEL + h * HEAD_E;
    const float* xr = x + (rowbase + qrow) * D_MODEL;

    if (t < 64) qr[t] = Qf[(rowbase + qrow) * D_MODEL + h * HEAD_E + t];
    float xreg[8];
#pragma unroll
    for (int jc = 0; jc < 8; ++jc) xreg[jc] = xr[(jc << 6) + l];
    __syncthreads();

    if (!tight) {
      // ---- exact f32 K-scan: wave w owns keys [256w, 256w+256) ----
      const int hf = l >> 5, k32 = l & 31;
      float4 q_r[8];
#pragma unroll
      for (int i = 0; i < 8; ++i) q_r[i] = *(const float4*)&qr[(hf * 8 + i) * 4];

      float* Ktw = &Kt[w][0];
      for (int ti = 0; ti < 8; ++ti) {
        const int kbase = w * 256 + ti * 32;
        __syncthreads();
#pragma unroll
        for (int i = 0; i < 8; ++i) {
          int f = (i << 6) + l;
          int r = f >> 4, c4 = f & 15;
          ((float4*)Ktw)[(r << 4) | (c4 ^ (r & 15))] =
              *(const float4*)&Kb[(size_t)(kbase + r) * D_MODEL + (c4 << 2)];
        }
        __syncthreads();
        float p0 = 0.f, p1 = 0.f;
#pragma unroll
        for (int i = 0; i < 8; i += 2) {
          int e4a = hf * 8 + i, e4b = e4a + 1;
          float4 ka = ((const float4*)Ktw)[(k32 << 4) | (e4a ^ (k32 & 15))];
          float4 kb = ((const float4*)Ktw)[(k32 << 4) | (e4b ^ (k32 & 15))];
          p0 += q_r[i].x*ka.x + q_r[i].y*ka.y + q_r[i].z*ka.z + q_r[i].w*ka.w;
          p1 += q_r[i+1].x*kb.x + q_r[i+1].y*kb.y + q_r[i+1].z*kb.z + q_r[i+1].w*kb.w;
        }
        float p = p0 + p1;
        p += __shfl_xor(p, 32);
        if (l < 32) Sf[kbase + k32] = p * 0.125f;
      }
      __syncthreads();
    }

    // ---- qd phase: wave w computes qdL[8w .. 8w+8) ----
    for (int sub = 0; sub < 8; ++sub) {
      const int he = w * 8 + sub;
      const float* wqr = Wq + (size_t)(h * HEAD_E + he) * D_MODEL;
      double p = 0.0;
#pragma unroll
      for (int jc = 0; jc < 8; ++jc)
        p += (double)wqr[(jc << 6) + l] * (double)xreg[jc];
#pragma unroll
      for (int off = 1; off < 64; off <<= 1) p += __shfl_xor(p, off);
      if (l == 0) qdL[he] = p + (double)bq[h * HEAD_E + he];
    }
    __syncthreads();                            // qdL complete

    // ---- u phase: thread t owns j=t; coalesced column accumulate ----
    {
      double u = 0.0;
#pragma unroll 8
      for (int e = 0; e < 64; ++e)
        u += qdL[e] * (double)Wk[(size_t)(h * HEAD_E + e) * D_MODEL + t];
      uL[t] = u;
    }

    // ---- candidate set: from candbuf (tight) or bisect+compact (scan) ----
    if (tight) {
      if (t < 64) ciL[t] = (int)candbuf[(size_t)s * 64 + t];
      if (t == 0) C2s = candC2[s];
    } else if (w == 0) {
      float v[32];
#pragma unroll
      for (int j = 0; j < 32; ++j) v[j] = Sf[(j << 6) + l];

      float hiv = v[0], lov = v[0];
#pragma unroll
      for (int j = 1; j < 32; ++j) { hiv = fmaxf(hiv, v[j]); lov = fminf(lov, v[j]); }
#pragma unroll
      for (int off = 1; off < 64; off <<= 1) {
        hiv = fmaxf(hiv, __shfl_xor(hiv, off));
        lov = fminf(lov, __shfl_xor(lov, off));
      }
      lov -= 1e-3f;
      for (int it = 0; it < 30; ++it) {
        int c = 0;
#pragma unroll
        for (int j = 0; j < 32; ++j) c += (v[j] >= lov) ? 1 : 0;
#pragma unroll
        for (int off = 1; off < 64; off <<= 1) c += __shfl_xor(c, off);
        if (c <= 64) break;
        float mid = 0.5f * (lov + hiv);
        int cm = 0;
#pragma unroll
        for (int j = 0; j < 32; ++j) cm += (v[j] >= mid) ? 1 : 0;
#pragma unroll
        for (int off = 1; off < 64; off <<= 1) cm += __shfl_xor(cm, off);
        if (cm >= 40) lov = mid; else hiv = mid;
      }

      int bb = 0;
#pragma unroll
      for (int j = 0; j < 32; ++j) {
        bool in = (v[j] >= lov);
        unsigned long long mk = __ballot(in);
        if (in) {
          int pos = bb + (int)__popcll(mk & ((1ull << l) - 1ull));
          if (pos < 64) ciL[pos] = (j << 6) + l;
        }
        bb += (int)__popcll(mk);
      }
      if (l == 0) C2s = (bb < 64) ? bb : 64;
    }
    __syncthreads();                            // uL, ciL, C2s complete

    const int C2 = C2s;

    // qkb (per wave, from qdL)
    double qkb = qdL[l] * (double)bk[h * HEAD_E + l];
#pragma unroll
    for (int off = 1; off < 64; off <<= 1) qkb += __shfl_xor(qkb, off);

    // ---- s_c phase: wave w owns candidates 8w .. 8w+8 ----
    for (int sub = 0; sub < 8; ++sub) {
      const int c = w * 8 + sub;
      const int row = (c < C2) ? (ciL[c] & (SEQ_L - 1)) : 0;
      const float* xc = x + (rowbase + row) * D_MODEL + l;
      double p = 0.0;
#pragma unroll
      for (int jc = 0; jc < 8; ++jc)
        p += uL[(jc << 6) + l] * (double)xc[jc << 6];
#pragma unroll
      for (int off = 1; off < 64; off <<= 1) p += __shfl_xor(p, off);
      if (l == 0) dL[c] = (c < C2) ? (qkb + p) * 0.125 : -1.0e300;
    }
    __syncthreads();                            // dL complete

    // ---- rank / softmax / PV on wave 0 ----
    if (w == 0) {
      double d = dL[l];
      int myi = (l < C2) ? ciL[l] : (2 * SEQ_L + l);
      double mxd = -1.0e300; int rank = 0;
      for (int j = 0; j < 64; ++j) {
        double dj = dL[j];
        int    ij = (j < C2) ? ciL[j] : (2 * SEQ_L + j);
        if (dj > mxd) mxd = dj;
        rank += (dj > d) || ((dj == d) && (ij < myi));
      }
      float myw = (l < C2 && rank < KSEL) ? __expf((float)(d - mxd)) : 0.f;

      float psum = myw;
#pragma unroll
      for (int off = 1; off < 64; off <<= 1) psum += __shfl_xor(psum, off);
      const float inv = 1.0f / psum;

      const float* Vb = Vf + rowbase * D_MODEL + h * HEAD_E;
      float acc = 0.f;
      for (int j0 = 0; j0 < 64; j0 += 8) {
        float wv8[8]; const float* vp8[8];
#pragma unroll
        for (int u8 = 0; u8 < 8; ++u8) {
          wv8[u8] = __shfl(myw, j0 + u8);
          int sj = __shfl(myi, j0 + u8) & (SEQ_L - 1);
          vp8[u8] = Vb + (size_t)sj * D_MODEL + l;
        }
        float vv8[8];
#pragma unroll
        for (int u8 = 0; u8 < 8; ++u8) vv8[u8] = *vp8[u8];
#pragma unroll
        for (int u8 = 0; u8 < 8; ++u8) acc = fmaf(wv8[u8], vv8[u8], acc);
      }
      AO[(rowbase + qrow) * D_MODEL + h * HEAD_E + l] = acc * inv;
    }
    __syncthreads();                            // protect LDS before next query
  }
}

// ---------------------------------------------------------------------------
extern "C" void kernel_launch(void* const* d_in, const int* in_sizes, int n_in,
                              void* d_out, int out_size, void* d_ws, size_t ws_size,
                              hipStream_t stream) {
  const float* x  = (const float*)d_in[0];
  const float* Wq = (const float*)d_in[1];
  const float* bq = (const float*)d_in[2];
  const float* Wk = (const float*)d_in[3];
  const float* bk = (const float*)d_in[4];
  const float* Wv = (const float*)d_in[5];
  const float* bv = (const float*)d_in[6];
  const float* Wo = (const float*)d_in[7];
  const float* bo = (const float*)d_in[8];
  float* out = (float*)d_out;

  char* ws = (char*)d_ws;
  const size_t MATB = (size_t)M_ROWS * D_MODEL * 4;  // 8 MB
  float* Qf = (float*)ws;
  float* Kf = (float*)(ws + MATB);
  float* Vf = (float*)(ws + 2 * MATB);
  float* AO = (float*)(ws + 3 * MATB);
  unsigned short* Qh  = (unsigned short*)(ws + 4 * MATB);                // 4 MB
  unsigned short* Kh  = (unsigned short*)(ws + 4 * MATB + MATB / 2);     // 4 MB
  unsigned short* Qlo = (unsigned short*)(ws + 5 * MATB);                // 4 MB
  unsigned short* Klo = (unsigned short*)(ws + 5 * MATB + MATB / 2);     // 4 MB
  float* kemax = (float*)(ws + 6 * MATB);                                // 4 KB
  int* nflag   = (int*)(ws + 6 * MATB + 4096);
  int* flagged = (int*)(ws + 6 * MATB + 8192);                           // 128 KB
  short* candbuf = (short*)(ws + 6 * MATB + 8192 + 131072);              // 512 KB
  int*   candC2  = (int*)(ws + 6 * MATB + 8192 + 131072 + FSLOTS * 128); // 16 KB

  hipMemsetAsync(nflag, 0, 64, stream);

  dim3 qkvgrid(D_MODEL / 64, M_ROWS / 64, 3);   // (8, 64, 3)
  gemm_qkv_kernel<<<qkvgrid, 256, 0, stream>>>(
      x, Wq, bq, Wk, bk, Wv, bv, Qf, Kf, Vf, Qh, Kh, Qlo, Klo);

  kemax_kernel<<<dim3(BATCH * N_HEADS), 256, 0, stream>>>(Kf, kemax);

  attn_main<<<dim3(SEQ_L / 16 * BATCH * N_HEADS), 512, 0, stream>>>(
      Qf, Kf, Vf, Qh, Kh, Qlo, Klo, kemax, AO, nflag, flagged, candbuf, candC2);

  attn_fixup<<<dim3(1024), 512, 0, stream>>>(
      Qf, Kf, Vf, x, Wq, bq, Wk, bk, AO, nflag, flagged, candbuf, candC2);

  dim3 ggrid(D_MODEL / 64, M_ROWS / 64);        // (8, 64)
  gemm_bias_kernel<<<ggrid, 256, 0, stream>>>(AO, Wo, bo, out, M_ROWS, D_MODEL, D_MODEL);
}